// Round 1
// baseline (292.694 us; speedup 1.0000x reference)
//
#include <hip/hip_runtime.h>

#define B_    2
#define T_    2048
#define C_    1024
#define H_    16
#define DH_   64
#define M_    (B_ * T_)        // 4096 tokens
#define NQKV  (3 * C_)         // 3072

typedef __bf16 bf16;
typedef __bf16 bf16x4 __attribute__((ext_vector_type(4)));
typedef __bf16 bf16x8 __attribute__((ext_vector_type(8)));
typedef float  f32x4  __attribute__((ext_vector_type(4)));

// async global->LDS, 16B per lane (global_load_lds_dwordx4).
// LDS dest must be wave-uniform base + lane*16 (no per-lane scatter).
__device__ __forceinline__ void async16(const void* g, void* l) {
  __builtin_amdgcn_global_load_lds(
      (const __attribute__((address_space(1))) void*)g,
      (__attribute__((address_space(3))) void*)l, 16, 0, 0);
}

// ---------------------------------------------------------------- converts
__global__ __launch_bounds__(256) void cvt_bf16_k(const float* __restrict__ in,
                                                  bf16* __restrict__ out) {
  const int i = (blockIdx.x * 256 + threadIdx.x) * 4;
  float4 v = *(const float4*)(in + i);
  bf16x4 o;
  o[0] = (bf16)v.x; o[1] = (bf16)v.y; o[2] = (bf16)v.z; o[3] = (bf16)v.w;
  *(bf16x4*)(out + i) = o;
}

// in: fp32 [R x C] row-major; out: bf16 [C x R] (i.e. transposed), both coalesced
__global__ __launch_bounds__(256) void transpose_cvt(const float* __restrict__ in,
                                                     bf16* __restrict__ out,
                                                     int R, int C) {
  __shared__ float tile[32][33];
  const int c0 = blockIdx.x * 32, r0 = blockIdx.y * 32;
  const int tx = threadIdx.x, ty = threadIdx.y;
#pragma unroll
  for (int j = 0; j < 4; j++)
    tile[ty + j * 8][tx] = in[(size_t)(r0 + ty + j * 8) * C + c0 + tx];
  __syncthreads();
#pragma unroll
  for (int j = 0; j < 4; j++)
    out[(size_t)(c0 + ty + j * 8) * R + r0 + tx] = (bf16)tile[tx][ty + j * 8];
}

// ---------------------------------------------------------------- GEMM
// C[M,N] = A[M,K=1024] * Bt[N,K]^T (+bias). 128x128 tile, BK=32, 4 waves (2x2 of 64x64).
// EPI 0: scatter into Q (pre-scaled by 0.125*log2e), K [B,H,T,dh], V^T [B,H,dh,T], all bf16.
// EPI 1: fp32 out[M,1024] + bias.
template <int EPI>
__global__ __launch_bounds__(256) void gemm128(
    const bf16* __restrict__ A, const bf16* __restrict__ Bt,
    const float* __restrict__ bias, float* __restrict__ outF,
    bf16* __restrict__ qb, bf16* __restrict__ kb, bf16* __restrict__ vtb) {
  constexpr int K = 1024;
  __shared__ alignas(16) bf16 As[128 * 32];
  __shared__ alignas(16) bf16 Bs[128 * 32];
  const int tid = threadIdx.x;
  const int lane = tid & 63, wv = tid >> 6;
  const int l15 = lane & 15, quad = lane >> 4;
  const int wm = (wv >> 1) * 64, wn = (wv & 1) * 64;
  const int m0 = blockIdx.x * 128, n0 = blockIdx.y * 128;

  f32x4 acc[4][4] = {};

  const bf16* ga = A + (size_t)(m0 + (tid >> 2)) * K + (tid & 3) * 8;
  const bf16* gb = Bt + (size_t)(n0 + (tid >> 2)) * K + (tid & 3) * 8;
  bf16* lA = As + tid * 8;
  bf16* lB = Bs + tid * 8;

  for (int k0 = 0; k0 < K; k0 += 32) {
    async16(ga + k0, lA);
    async16(ga + k0 + (size_t)64 * K, lA + 2048);
    async16(gb + k0, lB);
    async16(gb + k0 + (size_t)64 * K, lB + 2048);
    __syncthreads();
    bf16x8 af[4], bfr[4];
#pragma unroll
    for (int i = 0; i < 4; i++)
      af[i] = *(const bf16x8*)(As + (wm + i * 16 + l15) * 32 + quad * 8);
#pragma unroll
    for (int j = 0; j < 4; j++)
      bfr[j] = *(const bf16x8*)(Bs + (wn + j * 16 + l15) * 32 + quad * 8);
#pragma unroll
    for (int i = 0; i < 4; i++)
#pragma unroll
      for (int j = 0; j < 4; j++)
        acc[i][j] = __builtin_amdgcn_mfma_f32_16x16x32_bf16(af[i], bfr[j],
                                                            acc[i][j], 0, 0, 0);
    __syncthreads();
  }

  // epilogue: C/D layout col=lane&15, row=quad*4+reg
#pragma unroll
  for (int i = 0; i < 4; i++) {
#pragma unroll
    for (int j = 0; j < 4; j++) {
      const int gcol = n0 + wn + j * 16 + l15;
      const float bv = bias[gcol];
#pragma unroll
      for (int r = 0; r < 4; r++) {
        const int grow = m0 + wm + i * 16 + quad * 4 + r;
        float v = acc[i][j][r] + bv;
        if constexpr (EPI == 0) {
          const int which = gcol >> 10;          // 0=Q 1=K 2=V
          const int hn = gcol & 1023;
          const int h = hn >> 6, d = hn & 63;
          const int bb = grow >> 11, t = grow & 2047;
          const int head = bb * 16 + h;          // 0..31
          if (which == 0)
            qb[head * 131072 + t * 64 + d] = (bf16)(v * 0.1803368801f); // 1/8 * log2(e)
          else if (which == 1)
            kb[head * 131072 + t * 64 + d] = (bf16)v;
          else
            vtb[head * 131072 + d * 2048 + t] = (bf16)v;
        } else {
          outF[(size_t)grow * 1024 + gcol] = v;
        }
      }
    }
  }
}

// ---------------------------------------------------------------- flash attention
// grid (T/64, B*H). block 256 = 4 waves; wave w owns q rows [q0+16w, +16).
// Q pre-scaled so S is in log2 domain: softmax uses exp2 directly.
__global__ __launch_bounds__(256) void attn_k(const bf16* __restrict__ Q,
                                              const bf16* __restrict__ K,
                                              const bf16* __restrict__ Vt,
                                              bf16* __restrict__ O) {
  __shared__ alignas(16) bf16 Ks[64 * 64];   // [kt][d]
  __shared__ alignas(16) bf16 Vs[64 * 64];   // [d][kt]
  __shared__ alignas(16) bf16 Ps[4 * 16 * 64]; // per-wave P, [q16][kt64]
  const int tid = threadIdx.x, lane = tid & 63, wv = tid >> 6;
  const int l15 = lane & 15, quad = lane >> 4;
  const int bh = blockIdx.y;
  const int q0 = blockIdx.x * 64;
  const bf16* Qb = Q + (size_t)bh * 131072;
  const bf16* Kb = K + (size_t)bh * 131072;
  const bf16* Vb = Vt + (size_t)bh * 131072;

  // A-operand: A[m=lane&15][k=quad*8+j]
  const int qrow = q0 + wv * 16 + l15;
  bf16x8 aq0 = *(const bf16x8*)(Qb + qrow * 64 + quad * 8);
  bf16x8 aq1 = *(const bf16x8*)(Qb + qrow * 64 + 32 + quad * 8);

  f32x4 o[4] = {};
  float mrow[4] = {-3.0e38f, -3.0e38f, -3.0e38f, -3.0e38f};
  float lrow[4] = {0.f, 0.f, 0.f, 0.f};

  const bf16* gk = Kb + (tid >> 3) * 64 + (tid & 7) * 8;
  const bf16* gv = Vb + (tid >> 3) * 2048 + (tid & 7) * 8;
  bf16* lK = Ks + tid * 8;
  bf16* lV = Vs + tid * 8;
  bf16* Pw = Ps + wv * 1024;
  const int qbase = q0 + wv * 16 + quad * 4;

  for (int kt0 = 0; kt0 <= q0; kt0 += 64) {
    async16(gk + kt0 * 64, lK);
    async16(gk + kt0 * 64 + 32 * 64, lK + 2048);
    async16(gv + kt0, lV);
    async16(gv + kt0 + 32 * 2048, lV + 2048);
    __syncthreads();

    // S = Q K^T  (16 x 64), 2 k-chunks x 4 n-frags
    f32x4 s[4] = {};
#pragma unroll
    for (int kc = 0; kc < 2; kc++) {
      bf16x8 a = kc ? aq1 : aq0;
#pragma unroll
      for (int nf = 0; nf < 4; nf++) {
        bf16x8 bk = *(const bf16x8*)(Ks + (nf * 16 + l15) * 64 + kc * 32 + quad * 8);
        s[nf] = __builtin_amdgcn_mfma_f32_16x16x32_bf16(a, bk, s[nf], 0, 0, 0);
      }
    }

    const bool diag = (kt0 == q0);  // only the diagonal tile needs masking
#pragma unroll
    for (int r = 0; r < 4; r++) {
      const int q = qbase + r;
      float mx = -3.0e38f;
#pragma unroll
      for (int nf = 0; nf < 4; nf++) {
        float v = s[nf][r];
        if (diag) {
          const int kt = kt0 + nf * 16 + l15;
          v = (kt <= q) ? v : -3.0e38f;
          s[nf][r] = v;
        }
        mx = fmaxf(mx, v);
      }
      mx = fmaxf(mx, __shfl_xor(mx, 1));
      mx = fmaxf(mx, __shfl_xor(mx, 2));
      mx = fmaxf(mx, __shfl_xor(mx, 4));
      mx = fmaxf(mx, __shfl_xor(mx, 8));
      const float mnew = fmaxf(mrow[r], mx);
      const float alpha = __builtin_amdgcn_exp2f(mrow[r] - mnew);
      float psum = 0.f;
#pragma unroll
      for (int nf = 0; nf < 4; nf++) {
        const float pv = __builtin_amdgcn_exp2f(s[nf][r] - mnew);
        psum += pv;
        Pw[(quad * 4 + r) * 64 + nf * 16 + l15] = (bf16)pv;
      }
      psum += __shfl_xor(psum, 1);
      psum += __shfl_xor(psum, 2);
      psum += __shfl_xor(psum, 4);
      psum += __shfl_xor(psum, 8);
      lrow[r] = lrow[r] * alpha + psum;
      mrow[r] = mnew;
#pragma unroll
      for (int nf = 0; nf < 4; nf++) o[nf][r] *= alpha;
    }
    __syncthreads();  // P visible (and S-phase reads of Ks complete)

    // O += P V : A-frags from Pw, B-frags from Vs ([d][kt])
    bf16x8 pa0 = *(const bf16x8*)(Pw + l15 * 64 + quad * 8);
    bf16x8 pa1 = *(const bf16x8*)(Pw + l15 * 64 + 32 + quad * 8);
#pragma unroll
    for (int kc = 0; kc < 2; kc++) {
      bf16x8 pa = kc ? pa1 : pa0;
#pragma unroll
      for (int nf = 0; nf < 4; nf++) {
        bf16x8 bv = *(const bf16x8*)(Vs + (nf * 16 + l15) * 64 + kc * 32 + quad * 8);
        o[nf] = __builtin_amdgcn_mfma_f32_16x16x32_bf16(pa, bv, o[nf], 0, 0, 0);
      }
    }
    __syncthreads();  // everyone done with Ks/Vs before next stage
  }

  // epilogue: O[b, t, h*64+d] bf16, normalized
  const int bb = bh >> 4, h = bh & 15;
#pragma unroll
  for (int r = 0; r < 4; r++) {
    const float inv = 1.0f / lrow[r];
    const int q = qbase + r;
#pragma unroll
    for (int nf = 0; nf < 4; nf++)
      O[(size_t)(bb * 2048 + q) * 1024 + h * 64 + nf * 16 + l15] =
          (bf16)(o[nf][r] * inv);
  }
}

// ---------------------------------------------------------------- launch
extern "C" void kernel_launch(void* const* d_in, const int* in_sizes, int n_in,
                              void* d_out, int out_size, void* d_ws, size_t ws_size,
                              hipStream_t stream) {
  const float* x     = (const float*)d_in[0];
  const float* Wqkv  = (const float*)d_in[1];
  const float* bqkv  = (const float*)d_in[2];
  const float* Wproj = (const float*)d_in[3];
  const float* bproj = (const float*)d_in[4];
  float* out = (float*)d_out;

  char* p = (char*)d_ws;
  bf16* xbf    = (bf16*)p; p += (size_t)M_ * C_ * 2;     // 8 MB
  bf16* wqkvT  = (bf16*)p; p += (size_t)NQKV * C_ * 2;   // 6 MB
  bf16* wprojT = (bf16*)p; p += (size_t)C_ * C_ * 2;     // 2 MB
  bf16* Qb     = (bf16*)p; p += (size_t)M_ * C_ * 2;     // 8 MB
  bf16* Kb     = (bf16*)p; p += (size_t)M_ * C_ * 2;     // 8 MB
  bf16* Vtb    = (bf16*)p; p += (size_t)M_ * C_ * 2;     // 8 MB
  bf16* AO     = (bf16*)p;                               // 8 MB (total 48 MB)

  cvt_bf16_k<<<M_ * C_ / 1024, 256, 0, stream>>>(x, xbf);
  transpose_cvt<<<dim3(NQKV / 32, C_ / 32), dim3(32, 8), 0, stream>>>(Wqkv, wqkvT, C_, NQKV);
  transpose_cvt<<<dim3(C_ / 32, C_ / 32), dim3(32, 8), 0, stream>>>(Wproj, wprojT, C_, C_);

  gemm128<0><<<dim3(M_ / 128, NQKV / 128), 256, 0, stream>>>(
      xbf, wqkvT, bqkv, nullptr, Qb, Kb, Vtb);

  attn_k<<<dim3(T_ / 64, B_ * H_), 256, 0, stream>>>(Qb, Kb, Vtb, AO);

  gemm128<1><<<dim3(M_ / 128, C_ / 128), 256, 0, stream>>>(
      AO, wprojT, bproj, out, nullptr, nullptr, nullptr);
}

// Round 2
// 215.253 us; speedup vs baseline: 1.3598x; 1.3598x over previous
//
#include <hip/hip_runtime.h>

#define B_    2
#define T_    2048
#define C_    1024
#define H_    16
#define DH_   64
#define M_    (B_ * T_)        // 4096 tokens
#define NQKV  (3 * C_)         // 3072

typedef __bf16 bf16;
typedef __bf16 bf16x4 __attribute__((ext_vector_type(4)));
typedef __bf16 bf16x8 __attribute__((ext_vector_type(8)));
typedef float  f32x4  __attribute__((ext_vector_type(4)));

// async global->LDS, 16B per lane (global_load_lds_dwordx4).
// LDS dest must be wave-uniform base + lane*16 (no per-lane scatter).
__device__ __forceinline__ void async16(const void* g, void* l) {
  __builtin_amdgcn_global_load_lds(
      (const __attribute__((address_space(1))) void*)g,
      (__attribute__((address_space(3))) void*)l, 16, 0, 0);
}

// ---------------------------------------------------------------- converts
__global__ __launch_bounds__(256) void cvt_bf16_k(const float* __restrict__ in,
                                                  bf16* __restrict__ out) {
  const int i = (blockIdx.x * 256 + threadIdx.x) * 4;
  float4 v = *(const float4*)(in + i);
  bf16x4 o;
  o[0] = (bf16)v.x; o[1] = (bf16)v.y; o[2] = (bf16)v.z; o[3] = (bf16)v.w;
  *(bf16x4*)(out + i) = o;
}

// in: fp32 [R x C] row-major; out: bf16 [C x R] (i.e. transposed), both coalesced
__global__ __launch_bounds__(256) void transpose_cvt(const float* __restrict__ in,
                                                     bf16* __restrict__ out,
                                                     int R, int C) {
  __shared__ float tile[32][33];
  const int c0 = blockIdx.x * 32, r0 = blockIdx.y * 32;
  const int tx = threadIdx.x, ty = threadIdx.y;
#pragma unroll
  for (int j = 0; j < 4; j++)
    tile[ty + j * 8][tx] = in[(size_t)(r0 + ty + j * 8) * C + c0 + tx];
  __syncthreads();
#pragma unroll
  for (int j = 0; j < 4; j++)
    out[(size_t)(c0 + ty + j * 8) * R + r0 + tx] = (bf16)tile[tx][ty + j * 8];
}

// ---------------------------------------------------------------- GEMM
// C[M,N] = A[M,K=1024] * Bt[N,K]^T (+bias). 128x128 tile, BK=32, 4 waves (2x2 of 64x64).
// LDS column-groups (16B) XOR-swizzled by (row>>1)&3: kills the 8-way bank
// conflict on ds_read_b128 (row stride 64B -> bank indep of row&~1).
// EPI 0: scatter into Q (pre-scaled by 0.125*log2e), K [B,H,T,dh], V^T [B,H,dh,T], bf16.
// EPI 1: fp32 out[M,1024] + bias.
template <int EPI>
__global__ __launch_bounds__(256) void gemm128(
    const bf16* __restrict__ A, const bf16* __restrict__ Bt,
    const float* __restrict__ bias, float* __restrict__ outF,
    bf16* __restrict__ qb, bf16* __restrict__ kb, bf16* __restrict__ vtb) {
  constexpr int K = 1024;
  __shared__ alignas(16) bf16 As[128 * 32];
  __shared__ alignas(16) bf16 Bs[128 * 32];
  const int tid = threadIdx.x;
  const int lane = tid & 63, wv = tid >> 6;
  const int l15 = lane & 15, quad = lane >> 4;
  const int wm = (wv >> 1) * 64, wn = (wv & 1) * 64;
  const int m0 = blockIdx.x * 128, n0 = blockIdx.y * 128;

  f32x4 acc[4][4] = {};

  const int arow = tid >> 2;                       // 0..63 (and +64)
  const int ag = (tid & 3) ^ ((arow >> 1) & 3);    // swizzled col group
  const bf16* ga = A + (size_t)(m0 + arow) * K + ag * 8;
  const bf16* gb = Bt + (size_t)(n0 + arow) * K + ag * 8;
  bf16* lA = As + tid * 8;
  bf16* lB = Bs + tid * 8;
  const int rg = (quad ^ ((l15 >> 1) & 3)) * 8;    // read-side swizzled group

  for (int k0 = 0; k0 < K; k0 += 32) {
    async16(ga + k0, lA);
    async16(ga + k0 + (size_t)64 * K, lA + 2048);
    async16(gb + k0, lB);
    async16(gb + k0 + (size_t)64 * K, lB + 2048);
    __syncthreads();
    bf16x8 af[4], bfr[4];
#pragma unroll
    for (int i = 0; i < 4; i++)
      af[i] = *(const bf16x8*)(As + (wm + i * 16 + l15) * 32 + rg);
#pragma unroll
    for (int j = 0; j < 4; j++)
      bfr[j] = *(const bf16x8*)(Bs + (wn + j * 16 + l15) * 32 + rg);
#pragma unroll
    for (int i = 0; i < 4; i++)
#pragma unroll
      for (int j = 0; j < 4; j++)
        acc[i][j] = __builtin_amdgcn_mfma_f32_16x16x32_bf16(af[i], bfr[j],
                                                            acc[i][j], 0, 0, 0);
    __syncthreads();
  }

  // epilogue: C/D layout col=lane&15, row=quad*4+reg
#pragma unroll
  for (int i = 0; i < 4; i++) {
#pragma unroll
    for (int j = 0; j < 4; j++) {
      const int gcol = n0 + wn + j * 16 + l15;
      const float bv = bias[gcol];
#pragma unroll
      for (int r = 0; r < 4; r++) {
        const int grow = m0 + wm + i * 16 + quad * 4 + r;
        float v = acc[i][j][r] + bv;
        if constexpr (EPI == 0) {
          const int which = gcol >> 10;          // 0=Q 1=K 2=V
          const int hn = gcol & 1023;
          const int h = hn >> 6, d = hn & 63;
          const int bb = grow >> 11, t = grow & 2047;
          const int head = bb * 16 + h;          // 0..31
          if (which == 0)
            qb[head * 131072 + t * 64 + d] = (bf16)(v * 0.1803368801f); // 1/8 * log2(e)
          else if (which == 1)
            kb[head * 131072 + t * 64 + d] = (bf16)v;
          else
            vtb[head * 131072 + d * 2048 + t] = (bf16)v;
        } else {
          outF[(size_t)grow * 1024 + gcol] = v;
        }
      }
    }
  }
}

// ---------------------------------------------------------------- flash attention
// 1D grid of 1024 blocks; qi interleaved heavy/light so round-robin CU
// assignment (stride 256) gives every CU ~66 tile-iters. 4 waves; wave w owns
// q rows [q0+16w, +16). K/V LDS column-groups XOR-swizzled by row&7 (row
// stride 128B -> unswizzled bank would be row-independent = 16-way conflict).
// P staged per-wave with row stride 72 (2-way, free). One barrier per iter.
__global__ __launch_bounds__(256) void attn_k(const bf16* __restrict__ Q,
                                              const bf16* __restrict__ K,
                                              const bf16* __restrict__ Vt,
                                              bf16* __restrict__ O) {
  __shared__ alignas(16) bf16 Ks[64 * 64];       // [kt][d], swizzled
  __shared__ alignas(16) bf16 Vs[64 * 64];       // [d][kt], swizzled
  __shared__ alignas(16) bf16 Ps[4 * 16 * 72];   // per-wave P, stride 72
  const int tid = threadIdx.x, lane = tid & 63, wv = tid >> 6;
  const int l15 = lane & 15, quad = lane >> 4;

  const int l = blockIdx.x;
  const int x = l & 31;
  const int qi = ((l >> 8) & 1) ? (31 - x) : x;  // heavy/light pairing
  const int bh = (l >> 5) & 31;
  const int q0 = qi * 64;

  const bf16* Qb = Q + (size_t)bh * 131072;
  const bf16* Kb = K + (size_t)bh * 131072;
  const bf16* Vb = Vt + (size_t)bh * 131072;

  // A-operand: A[m=lane&15][k=quad*8+j]
  const int qrow = q0 + wv * 16 + l15;
  bf16x8 aq0 = *(const bf16x8*)(Qb + qrow * 64 + quad * 8);
  bf16x8 aq1 = *(const bf16x8*)(Qb + qrow * 64 + 32 + quad * 8);

  f32x4 o[4] = {};
  float mrow[4] = {-3.0e38f, -3.0e38f, -3.0e38f, -3.0e38f};
  float lrow[4] = {0.f, 0.f, 0.f, 0.f};

  const int srow = tid >> 3;                     // 0..31 (and +32)
  const int sg = (tid & 7) ^ (srow & 7);         // swizzled col group (global side)
  const bf16* gk = Kb + srow * 64 + sg * 8;
  const bf16* gv = Vb + srow * 2048 + sg * 8;
  bf16* lK = Ks + tid * 8;
  bf16* lV = Vs + tid * 8;
  bf16* Pw = Ps + wv * (16 * 72);
  const int qbase = q0 + wv * 16 + quad * 4;
  const int swz = l15 & 7;                       // read-side row swizzle key

  for (int kt0 = 0; kt0 <= q0; kt0 += 64) {
    async16(gk + kt0 * 64, lK);
    async16(gk + kt0 * 64 + 32 * 64, lK + 2048);
    async16(gv + kt0, lV);
    async16(gv + kt0 + 32 * 2048, lV + 2048);
    __syncthreads();

    // S = Q K^T  (16 x 64), 2 k-chunks x 4 n-frags
    f32x4 s[4] = {};
#pragma unroll
    for (int kc = 0; kc < 2; kc++) {
      bf16x8 a = kc ? aq1 : aq0;
#pragma unroll
      for (int nf = 0; nf < 4; nf++) {
        bf16x8 bk = *(const bf16x8*)(Ks + (nf * 16 + l15) * 64 +
                                     (((kc * 4 + quad) ^ swz) * 8));
        s[nf] = __builtin_amdgcn_mfma_f32_16x16x32_bf16(a, bk, s[nf], 0, 0, 0);
      }
    }

    const bool diag = (kt0 == q0);  // only the diagonal tile needs masking
#pragma unroll
    for (int r = 0; r < 4; r++) {
      const int q = qbase + r;
      float mx = -3.0e38f;
#pragma unroll
      for (int nf = 0; nf < 4; nf++) {
        float v = s[nf][r];
        if (diag) {
          const int kt = kt0 + nf * 16 + l15;
          v = (kt <= q) ? v : -3.0e38f;
          s[nf][r] = v;
        }
        mx = fmaxf(mx, v);
      }
      mx = fmaxf(mx, __shfl_xor(mx, 1));
      mx = fmaxf(mx, __shfl_xor(mx, 2));
      mx = fmaxf(mx, __shfl_xor(mx, 4));
      mx = fmaxf(mx, __shfl_xor(mx, 8));
      const float mnew = fmaxf(mrow[r], mx);
      const float alpha = __builtin_amdgcn_exp2f(mrow[r] - mnew);
      float psum = 0.f;
#pragma unroll
      for (int nf = 0; nf < 4; nf++) {
        const float pv = __builtin_amdgcn_exp2f(s[nf][r] - mnew);
        psum += pv;
        Pw[(quad * 4 + r) * 72 + nf * 16 + l15] = (bf16)pv;
      }
      psum += __shfl_xor(psum, 1);
      psum += __shfl_xor(psum, 2);
      psum += __shfl_xor(psum, 4);
      psum += __shfl_xor(psum, 8);
      lrow[r] = lrow[r] * alpha + psum;
      mrow[r] = mnew;
#pragma unroll
      for (int nf = 0; nf < 4; nf++) o[nf][r] *= alpha;
    }
    // NOTE: no barrier here — Pw is per-wave (same-wave DS ordering suffices).

    // O += P V : A-frags from Pw, B-frags from Vs ([d][kt])
    bf16x8 pa0 = *(const bf16x8*)(Pw + l15 * 72 + quad * 8);
    bf16x8 pa1 = *(const bf16x8*)(Pw + l15 * 72 + 32 + quad * 8);
#pragma unroll
    for (int kc = 0; kc < 2; kc++) {
      bf16x8 pa = kc ? pa1 : pa0;
#pragma unroll
      for (int nf = 0; nf < 4; nf++) {
        bf16x8 bv = *(const bf16x8*)(Vs + (nf * 16 + l15) * 64 +
                                     (((kc * 4 + quad) ^ swz) * 8));
        o[nf] = __builtin_amdgcn_mfma_f32_16x16x32_bf16(pa, bv, o[nf], 0, 0, 0);
      }
    }
    __syncthreads();  // everyone done with Ks/Vs before next staging
  }

  // epilogue: O[b, t, h*64+d] bf16, normalized
  const int bb = bh >> 4, h = bh & 15;
#pragma unroll
  for (int r = 0; r < 4; r++) {
    const float inv = 1.0f / lrow[r];
    const int q = qbase + r;
#pragma unroll
    for (int nf = 0; nf < 4; nf++)
      O[(size_t)(bb * 2048 + q) * 1024 + h * 64 + nf * 16 + l15] =
          (bf16)(o[nf][r] * inv);
  }
}

// ---------------------------------------------------------------- launch
extern "C" void kernel_launch(void* const* d_in, const int* in_sizes, int n_in,
                              void* d_out, int out_size, void* d_ws, size_t ws_size,
                              hipStream_t stream) {
  const float* x     = (const float*)d_in[0];
  const float* Wqkv  = (const float*)d_in[1];
  const float* bqkv  = (const float*)d_in[2];
  const float* Wproj = (const float*)d_in[3];
  const float* bproj = (const float*)d_in[4];
  float* out = (float*)d_out;

  char* p = (char*)d_ws;
  bf16* xbf    = (bf16*)p; p += (size_t)M_ * C_ * 2;     // 8 MB
  bf16* wqkvT  = (bf16*)p; p += (size_t)NQKV * C_ * 2;   // 6 MB
  bf16* wprojT = (bf16*)p; p += (size_t)C_ * C_ * 2;     // 2 MB
  bf16* Qb     = (bf16*)p; p += (size_t)M_ * C_ * 2;     // 8 MB
  bf16* Kb     = (bf16*)p; p += (size_t)M_ * C_ * 2;     // 8 MB
  bf16* Vtb    = (bf16*)p; p += (size_t)M_ * C_ * 2;     // 8 MB
  bf16* AO     = (bf16*)p;                               // 8 MB (total 48 MB)

  cvt_bf16_k<<<M_ * C_ / 1024, 256, 0, stream>>>(x, xbf);
  transpose_cvt<<<dim3(NQKV / 32, C_ / 32), dim3(32, 8), 0, stream>>>(Wqkv, wqkvT, C_, NQKV);
  transpose_cvt<<<dim3(C_ / 32, C_ / 32), dim3(32, 8), 0, stream>>>(Wproj, wprojT, C_, C_);

  gemm128<0><<<dim3(M_ / 128, NQKV / 128), 256, 0, stream>>>(
      xbf, wqkvT, bqkv, nullptr, Qb, Kb, Vtb);

  attn_k<<<1024, 256, 0, stream>>>(Qb, Kb, Vtb, AO);

  gemm128<1><<<dim3(M_ / 128, C_ / 128), 256, 0, stream>>>(
      AO, wprojT, bproj, out, nullptr, nullptr, nullptr);
}